// Round 12
// baseline (174.711 us; speedup 1.0000x reference)
//
#include <hip/hip_runtime.h>
#include <hip/hip_fp16.h>
#include <math.h>

#define T_LEN 8192
#define CHN 128
#define BATCH 16
#define NKCHUNK 32   // k-chunk = 256 -> grid 16x32 = 512 blocks (2/CU, VGPR-capped)
#define KSTAGE 32    // k elems per LDS stage -> NITER 8
#define NITER (T_LEN / NKCHUNK / KSTAGE)   // = 8 stage iterations per block

typedef short bf16x8 __attribute__((ext_vector_type(8)));
typedef float f32x16 __attribute__((ext_vector_type(16)));

// Native-vector complex type -> packed v_pk_* fp32 codegen (R8: -3 us fft).
typedef float cplx __attribute__((ext_vector_type(2)));
__device__ __forceinline__ cplx C2(float x, float y) { cplx r; r.x = x; r.y = y; return r; }

#define SIN8 0.3826834323650898f
#define COS8 0.9238795325112868f

// zc/zs K-CHUNKED layout [b][t>>6][chan][t&63] (R17: contiguous gram reads).
#define TCHUNK 8192              // ushorts per [tc] slab: 128 chan x 64 k
#define BPLANE (128 * TCHUNK)    // ushorts per batch per plane (= CHN*T_LEN)

// gram LDS geometry: KSTAGE=32 -> plane = 128 rows x 32 k = 8 KiB.
// Column-major swizzle: chunk (r,c) at group offset (c^(r&3))*256B +
// (r&15)*16B within the (r>>4) 1-KiB group. Read bank pattern identical to
// the measured-0-conflict padded layout (R6).
#define GSP 4096                 // ushorts per plane (8 KiB)
#define GBUF (2 * GSP)           // ushorts per buffer (zc+zs planes, 16 KiB)

typedef const __attribute__((address_space(1))) uint gld_src_t;
typedef __attribute__((address_space(3))) uint gld_dst_t;

__device__ __forceinline__ ushort f2bf(float f) {
    unsigned u = __float_as_uint(f);
    unsigned r = (u + 0x7fffu + ((u >> 16) & 1u)) >> 16;
    return (ushort)r;
}

__device__ __forceinline__ void barrier_lds_only() {
    asm volatile("s_waitcnt lgkmcnt(0)" ::: "memory");
    __builtin_amdgcn_s_barrier();
}

__device__ __forceinline__ cplx cmul(cplx a, cplx b) {
    cplx t = a.yy * b.yx;            // {ay*by, ay*bx}  (pk_mul)
    cplx r = a.xx * b;               // {ax*bx, ax*by}  (pk_mul)
    return C2(r.x - t.x, r.y + t.y);
}

__device__ __forceinline__ void r4f(cplx x0, cplx x1, cplx x2, cplx x3,
                                    cplx wa, cplx wb, cplx wc,
                                    cplx& y0, cplx& y1, cplx& y2, cplx& y3) {
    cplx t0 = x0 + x2, t1 = x0 - x2;
    cplx t2 = x1 + x3, t3 = x1 - x3;
    y0 = t0 + t2;
    y1 = cmul(t0 - t2, wb);
    y2 = cmul(C2(t1.x + t3.y, t1.y - t3.x), wa);
    y3 = cmul(C2(t1.x - t3.y, t1.y + t3.x), wc);
}

__device__ __forceinline__ void r4i(cplx x0, cplx x1, cplx x2, cplx x3,
                                    cplx wa, cplx wb, cplx wc,
                                    cplx& y0, cplx& y1, cplx& y2, cplx& y3) {
    cplx a1 = cmul(x1, wb);
    cplx a2 = cmul(x2, wa);
    cplx a3 = cmul(x3, wc);
    cplx u0 = x0 + a1, u1 = x0 - a1;
    cplx p = a2 + a3;
    cplx m = C2(-(a2.y - a3.y), a2.x - a3.x);
    y0 = u0 + p; y2 = u0 - p;
    y1 = u1 + m; y3 = u1 - m;
}

__device__ __forceinline__ void r8f(const cplx* x, float sn, float cs, cplx* y) {
    const float r22 = 0.70710678118654752f;
    cplx w1 = C2(cs, sn);
    cplx w2 = C2(cs * cs - sn * sn, 2.f * cs * sn);
    cplx w4 = cmul(w2, w2);
    cplx w6 = cmul(w4, w2);
    cplx u0 = x[0] + x[4], u1 = x[1] + x[5], u2 = x[2] + x[6], u3 = x[3] + x[7];
    cplx e0 = cmul(x[0] - x[4], w1);
    cplx e1 = cmul(x[1] - x[5], w1);
    cplx e2 = cmul(x[2] - x[6], w1);
    cplx e3 = cmul(x[3] - x[7], w1);
    cplx v0 = e0;
    cplx v1 = C2(r22 * (e1.x + e1.y), r22 * (e1.y - e1.x));
    cplx v2 = C2(e2.y, -e2.x);
    cplx v3 = C2(r22 * (e3.y - e3.x), -r22 * (e3.x + e3.y));
    r4f(u0, u1, u2, u3, w2, w4, w6, y[0], y[1], y[2], y[3]);
    r4f(v0, v1, v2, v3, w2, w4, w6, y[4], y[5], y[6], y[7]);
}

// Pass-A specialization: inputs pure real (imag = 0).
__device__ __forceinline__ void r8f_real(const float* x, float sn, float cs, cplx* y) {
    const float r22 = 0.70710678118654752f;
    cplx w2 = C2(cs * cs - sn * sn, 2.f * cs * sn);
    cplx w4 = cmul(w2, w2);
    cplx w6 = cmul(w4, w2);
    float u0 = x[0] + x[4], u1 = x[1] + x[5], u2 = x[2] + x[6], u3 = x[3] + x[7];
    float d0 = x[0] - x[4], d1 = x[1] - x[5], d2 = x[2] - x[6], d3 = x[3] - x[7];
    cplx e1 = C2(d1 * cs, d1 * sn);
    cplx e2 = C2(d2 * cs, d2 * sn);
    cplx e3 = C2(d3 * cs, d3 * sn);
    cplx v0 = C2(d0 * cs, d0 * sn);
    cplx v1 = C2(r22 * (e1.x + e1.y), r22 * (e1.y - e1.x));
    cplx v2 = C2(e2.y, -e2.x);
    cplx v3 = C2(r22 * (e3.y - e3.x), -r22 * (e3.x + e3.y));
    float t0 = u0 + u2, t1 = u0 - u2, t2 = u1 + u3, t3 = u1 - u3;
    y[0] = C2(t0 + t2, 0.f);
    float s1 = t0 - t2;
    y[1] = C2(s1 * w4.x, s1 * w4.y);
    y[2] = cmul(C2(t1, -t3), w2);
    y[3] = cmul(C2(t1, t3), w6);
    r4f(v0, v1, v2, v3, w2, w4, w6, y[4], y[5], y[6], y[7]);
}

__device__ __forceinline__ void r8i(const cplx* x, float sn, float cs, cplx* y) {
    const float r22 = 0.70710678118654752f;
    cplx w1 = C2(cs, sn);
    cplx w2 = C2(cs * cs - sn * sn, 2.f * cs * sn);
    cplx w4 = cmul(w2, w2);
    cplx w6 = cmul(w4, w2);
    cplx g0, g1, g2, g3, g4, g5, g6, g7;
    r4i(x[0], x[1], x[2], x[3], w2, w4, w6, g0, g1, g2, g3);
    r4i(x[4], x[5], x[6], x[7], w2, w4, w6, g4, g5, g6, g7);
    cplx t0 = cmul(g4, w1);
    cplx e1 = cmul(g5, w1);
    cplx e2 = cmul(g6, w1);
    cplx e3 = cmul(g7, w1);
    cplx t1 = C2(r22 * (e1.x - e1.y), r22 * (e1.x + e1.y));
    cplx t2 = C2(-e2.y, e2.x);
    cplx t3 = C2(-r22 * (e3.x + e3.y), r22 * (e3.x - e3.y));
    y[0] = g0 + t0; y[4] = g0 - t0;
    y[1] = g1 + t1; y[5] = g1 - t1;
    y[2] = g2 + t2; y[6] = g2 - t2;
    y[3] = g3 + t3; y[7] = g3 - t3;
}

// One block per (b,c) row, 512 threads — R9 version (74-75 us, VGPR 52,
// reproduced on 3 containers). R10: twiddle hoisting kept ~32 VGPR live
// across barriers, +25% wall with identical VALU work — fft is stall-bound;
// per-pass sincos is free. R1-R3: 1024-thread variants spill. UNCHANGED.
__global__ __launch_bounds__(512, 4) void fft_analytic_kernel(const float* __restrict__ x,
                                                              ushort* __restrict__ zc,
                                                              ushort* __restrict__ zs) {
    __shared__ __align__(16) cplx buf[T_LEN];   // 64 KiB
    const int tid = threadIdx.x;
    const int row = blockIdx.x;
    const float* xr = x + ((size_t)row << 13);

    // fwd pass Q=1024 fused with global load (x real; imag folds away)
    for (int s = 0; s < 2; ++s) {
        const int g = tid + (s << 9);
        float X[8];
        cplx Y[8];
#pragma unroll
        for (int c = 0; c < 8; ++c) X[c] = xr[g + (c << 10)];
        float sn, cs;
        __sincosf(-(float)M_PI / 4096.f * (float)g, &sn, &cs);
        r8f_real(X, sn, cs, Y);
#pragma unroll
        for (int c = 0; c < 8; ++c) buf[g + (c << 10)] = Y[c];
    }
    __syncthreads();

    // fwd LDS pass Q=128
    {
        const float astep = -(float)M_PI / 512.f;
        for (int s = 0; s < 2; ++s) {
            const int g = tid + (s << 9);
            const int j = g & 127;
            const int i = ((g & ~127) << 3) | j;
            cplx xx[8], yy[8];
#pragma unroll
            for (int c = 0; c < 8; ++c) xx[c] = buf[i + c * 128];
            float sn, cs;
            __sincosf(astep * (float)j, &sn, &cs);
            r8f(xx, sn, cs, yy);
#pragma unroll
            for (int c = 0; c < 8; ++c) buf[i + c * 128] = yy[c];
        }
        __syncthreads();
    }

    // fwd LDS pass Q=16: plain reads, swizzled writes (slot = idx ^ 2c)
    {
        const float astep = -(float)M_PI / 64.f;
        for (int s = 0; s < 2; ++s) {
            const int g = tid + (s << 9);
            const int j = g & 15;
            const int i = ((g & ~15) << 3) | j;
            cplx xx[8], yy[8];
#pragma unroll
            for (int c = 0; c < 8; ++c) xx[c] = buf[i + c * 16];
            float sn, cs;
            __sincosf(astep * (float)j, &sn, &cs);
            r8f(xx, sn, cs, yy);
#pragma unroll
            for (int c = 0; c < 8; ++c) buf[(i + c * 16) ^ (2 * c)] = yy[c];
        }
        __syncthreads();
    }

    // register-local middle: thread owns elements [16*tid, 16*tid+16).
    {
        cplx v[16];
        float4* bb = (float4*)buf;
        const int K = tid & 7;
#pragma unroll
        for (int p = 0; p < 8; ++p) {
            float4 f = bb[8 * tid + (p ^ K)];
            v[2 * p]     = C2(f.x, f.y);
            v[2 * p + 1] = C2(f.z, f.w);
        }
        cplx xe[8], xo[8], E[8], O[8], t[8];
#pragma unroll
        for (int c = 0; c < 8; ++c) { xe[c] = v[2 * c]; xo[c] = v[2 * c + 1]; }
        r8f(xe, 0.f, 1.f, E);
        r8f(xo, -SIN8, COS8, O);
#pragma unroll
        for (int c = 0; c < 8; ++c) t[c] = E[c] + O[c];   // dist-1 + mask fuse
        r8i(t, 0.f, 1.f, xe);
        r8i(t, SIN8, COS8, xo);
#pragma unroll
        for (int p = 0; p < 8; ++p)
            bb[8 * tid + (p ^ K)] = make_float4(xe[p].x, xe[p].y, xo[p].x, xo[p].y);
    }
    __syncthreads();

    // inv LDS pass Q=16: swizzled reads, plain writes
    {
        const float astep = (float)M_PI / 64.f;
        for (int s = 0; s < 2; ++s) {
            const int g = tid + (s << 9);
            const int j = g & 15;
            const int i = ((g & ~15) << 3) | j;
            cplx xx[8], yy[8];
#pragma unroll
            for (int c = 0; c < 8; ++c) xx[c] = buf[(i + c * 16) ^ (2 * c)];
            float sn, cs;
            __sincosf(astep * (float)j, &sn, &cs);
            r8i(xx, sn, cs, yy);
#pragma unroll
            for (int c = 0; c < 8; ++c) buf[i + c * 16] = yy[c];
        }
        __syncthreads();
    }

    // inv LDS pass Q=128
    {
        const float astep = (float)M_PI / 512.f;
        for (int s = 0; s < 2; ++s) {
            const int g = tid + (s << 9);
            const int j = g & 127;
            const int i = ((g & ~127) << 3) | j;
            cplx xx[8], yy[8];
#pragma unroll
            for (int c = 0; c < 8; ++c) xx[c] = buf[i + c * 128];
            float sn, cs;
            __sincosf(astep * (float)j, &sn, &cs);
            r8i(xx, sn, cs, yy);
#pragma unroll
            for (int c = 0; c < 8; ++c) buf[i + c * 128] = yy[c];
        }
        __syncthreads();
    }

    // final inv pass Q=1024 fused with normalize + K-CHUNKED store:
    // element t -> plane[b][t>>6][chan][t&63]. 128 B/wave coalesced.
    {
        const size_t base = ((size_t)(row >> 7) * BPLANE) + (size_t)(row & 127) * 64;
        ushort* zcr = zc + base;
        ushort* zsr = zs + base;
        const int tk = tid & 63;
        const int tcb = tid >> 6;
        for (int s = 0; s < 2; ++s) {
            const int g = tid + (s << 9);
            cplx xx[8], yy[8];
#pragma unroll
            for (int c = 0; c < 8; ++c) xx[c] = buf[g + (c << 10)];
            float sn, cs;
            __sincosf((float)M_PI / 4096.f * (float)g, &sn, &cs);
            r8i(xx, sn, cs, yy);
#pragma unroll
            for (int c = 0; c < 8; ++c) {
                cplx vv = yy[c];
                float n2 = vv.x * vv.x + vv.y * vv.y;
                float cc = 1.f, ss = 0.f;
                if (n2 > 0.f) { float inv = rsqrtf(n2); cc = vv.x * inv; ss = vv.y * inv; }
                const int tc = tcb + s * 8 + c * 16;          // t>>6
                zcr[(size_t)tc * TCHUNK + tk] = f2bf(cc);
                zsr[(size_t)tc * TCHUNK + tk] = f2bf(ss);
            }
        }
    }
}

// MFMA Gram partials — R19: DEPTH-4 DMA pipeline (4 x 16 KiB buffers =
// 64 KiB LDS). Corrected occupancy model: gram VGPR ~110 caps it at
// 2 blocks/CU REGARDLESS of LDS (waves/CU halves at 128 VGPR, m69) — so
// R18's depth-3 win was pipeline depth, not blocks/CU, and deeper costs
// nothing. Per-stage compute ~200 cyc vs ~900 cyc HBM latency: depth-3
// covered ~2 stages ahead; depth-4 covers 3. Steady vmcnt(6) (3 newer
// stages x 2 loads in flight), tail 4->2->0.
__global__ __launch_bounds__(512, 4) void gram_kernel(const ushort* __restrict__ zc,
                                                      const ushort* __restrict__ zs,
                                                      __half2* __restrict__ partial) {
    const int b = blockIdx.x, kc = blockIdx.y;
    const int tid = threadIdx.x;
    const int wave = tid >> 6;
    const int lane = tid & 63;
    const int wr = wave & 3, wcol = wave >> 2;
    const int lane31 = tid & 31;
    const int half = (tid >> 5) & 1;

    __shared__ __align__(16) ushort sZ[4 * GBUF];   // 64 KiB

    f32x16 accRe[2], accIm[2];
#pragma unroll
    for (int v = 0; v < 2; ++v)
#pragma unroll
        for (int r = 0; r < 16; ++r) { accRe[v][r] = 0.f; accIm[v][r] = 0.f; }

    // kc covers 4 global t-slabs; stage it covers half-slab (it&1) of slab (it>>1).
    const size_t base = (size_t)b * BPLANE + (size_t)kc * 4 * TCHUNK;

    const ushort* gsrc[2];
    int lbase[2];
#pragma unroll
    for (int q = 0; q < 2; ++q) {
        int L = (q * 8 + wave) * 64 + lane;   // 0..1023
        int plane = L >> 9;
        int P = L & 511;
        int g = P >> 6;
        int s = P & 63;
        int r = g * 16 + (s & 15);
        int c = (s >> 4) ^ (r & 3);
        gsrc[q] = (plane ? zs : zc) + base + (size_t)r * 64 + (size_t)c * 8;
        lbase[q] = (q * 8 + wave) * 512;
    }

#define STAGE(IT, BUF) do {                                                        \
        _Pragma("unroll")                                                          \
        for (int q = 0; q < 2; ++q)                                                \
            __builtin_amdgcn_global_load_lds(                                      \
                (gld_src_t*)(gsrc[q] + (size_t)((IT) >> 1) * TCHUNK                \
                                     + (size_t)((IT) & 1) * 32),                   \
                (gld_dst_t*)&sZ[(BUF) * GBUF + lbase[q]], 16, 0, 0);               \
    } while (0)

    STAGE(0, 0);
    STAGE(1, 1);
    STAGE(2, 2);
    STAGE(3, 3);

#pragma unroll
    for (int it = 0; it < NITER; ++it) {
        if (it <= NITER - 4)      { asm volatile("s_waitcnt vmcnt(6)" ::: "memory"); }
        else if (it == NITER - 3) { asm volatile("s_waitcnt vmcnt(4)" ::: "memory"); }
        else if (it == NITER - 2) { asm volatile("s_waitcnt vmcnt(2)" ::: "memory"); }
        else                      { asm volatile("s_waitcnt vmcnt(0)" ::: "memory"); }
        __builtin_amdgcn_sched_barrier(0);
        __builtin_amdgcn_s_barrier();

        const ushort* S = sZ + (it & 3) * GBUF;
#pragma unroll
        for (int kb = 0; kb < KSTAGE; kb += 16) {
            const int cA = (kb >> 3) + half;                   // chunk 0..3
            const int rowA = wr * 32 + lane31;
            const int aoff = ((rowA >> 4) << 9) + ((cA ^ (rowA & 3)) << 7) + ((rowA & 15) << 3);
            bf16x8 aC = *(const bf16x8*)&S[aoff];
            bf16x8 aS = *(const bf16x8*)&S[GSP + aoff];
            bf16x8 aCn;
#pragma unroll
            for (int r = 0; r < 8; ++r) aCn[r] = (short)(aC[r] ^ (short)0x8000);
            bf16x8 bC[2], bS[2];
#pragma unroll
            for (int v = 0; v < 2; ++v) {
                const int rowB = wcol * 64 + v * 32 + lane31;
                const int boff = ((rowB >> 4) << 9) + ((cA ^ (rowB & 3)) << 7) + ((rowB & 15) << 3);
                bC[v] = *(const bf16x8*)&S[boff];
                bS[v] = *(const bf16x8*)&S[GSP + boff];
            }
            accRe[0] = __builtin_amdgcn_mfma_f32_32x32x16_bf16(aC,  bC[0], accRe[0], 0, 0, 0);
            accRe[1] = __builtin_amdgcn_mfma_f32_32x32x16_bf16(aC,  bC[1], accRe[1], 0, 0, 0);
            accIm[0] = __builtin_amdgcn_mfma_f32_32x32x16_bf16(aS,  bC[0], accIm[0], 0, 0, 0);
            accIm[1] = __builtin_amdgcn_mfma_f32_32x32x16_bf16(aS,  bC[1], accIm[1], 0, 0, 0);
            accRe[0] = __builtin_amdgcn_mfma_f32_32x32x16_bf16(aS,  bS[0], accRe[0], 0, 0, 0);
            accRe[1] = __builtin_amdgcn_mfma_f32_32x32x16_bf16(aS,  bS[1], accRe[1], 0, 0, 0);
            accIm[0] = __builtin_amdgcn_mfma_f32_32x32x16_bf16(aCn, bS[0], accIm[0], 0, 0, 0);
            accIm[1] = __builtin_amdgcn_mfma_f32_32x32x16_bf16(aCn, bS[1], accIm[1], 0, 0, 0);
        }

        barrier_lds_only();
        if (it + 4 < NITER) STAGE(it + 4, it & 3);
    }
#undef STAGE

    // C/D layout (verified m74/m101): col=lane&31, row=(reg&3)+8*(reg>>2)+4*(lane>>5)
    __half2* pb = partial + ((size_t)(kc * BATCH + b) << 14);
#pragma unroll
    for (int v = 0; v < 2; ++v)
#pragma unroll
        for (int r = 0; r < 16; ++r) {
            int rrow = (r & 3) + 8 * (r >> 2) + 4 * half;
            int i = wr * 32 + rrow;
            int j = wcol * 64 + v * 32 + lane31;
            pb[i * CHN + j] = __floats2half2_rn(accRe[v][r], accIm[v][r]);
        }
}

// R19: vectorized reduce — 4 outputs/thread, uint4 (4 x half2) loads per
// chunk, float4 store. 256 blocks x 256 threads; 16 B/lane fully coalesced.
__global__ __launch_bounds__(256) void reduce_kernel(const __half2* __restrict__ partial,
                                                     float* __restrict__ out) {
    const size_t n = (size_t)BATCH * CHN * CHN;
    const size_t i4 = ((size_t)blockIdx.x * 256 + threadIdx.x) * 4;
    if (i4 >= n) return;
    float re[4] = {0.f, 0.f, 0.f, 0.f}, im[4] = {0.f, 0.f, 0.f, 0.f};
#pragma unroll
    for (int c = 0; c < NKCHUNK; ++c) {
        uint4 u = *(const uint4*)&partial[(size_t)c * n + i4];
        const __half2* h = (const __half2*)&u;
#pragma unroll
        for (int k = 0; k < 4; ++k) {
            float2 p = __half22float2(h[k]);
            re[k] += p.x;
            im[k] += p.y;
        }
    }
    float4 o;
    o.x = sqrtf(re[0] * re[0] + im[0] * im[0]) * (1.0f / (float)T_LEN);
    o.y = sqrtf(re[1] * re[1] + im[1] * im[1]) * (1.0f / (float)T_LEN);
    o.z = sqrtf(re[2] * re[2] + im[2] * im[2]) * (1.0f / (float)T_LEN);
    o.w = sqrtf(re[3] * re[3] + im[3] * im[3]) * (1.0f / (float)T_LEN);
    *(float4*)&out[i4] = o;
}

extern "C" void kernel_launch(void* const* d_in, const int* in_sizes, int n_in,
                              void* d_out, int out_size, void* d_ws, size_t ws_size,
                              hipStream_t stream) {
    const float* x = (const float*)d_in[0];
    float* out = (float*)d_out;

    const size_t plane_elems = (size_t)BATCH * CHN * T_LEN;                 // 16.8M
    ushort* zc = (ushort*)d_ws;                                             // 33.55 MB
    ushort* zs = zc + plane_elems;                                          // +33.55 MB
    __half2* partial = (__half2*)((char*)d_ws + 2 * plane_elems * sizeof(ushort)); // +33.55 MB (NKCHUNK=32)

    fft_analytic_kernel<<<BATCH * CHN, 512, 0, stream>>>(x, zc, zs);

    dim3 g2(BATCH, NKCHUNK);
    gram_kernel<<<g2, 512, 0, stream>>>(zc, zs, partial);

    const int n_out = BATCH * CHN * CHN;                                    // 262144
    reduce_kernel<<<n_out / (256 * 4), 256, 0, stream>>>(partial, out);
}

// Round 13
// 173.345 us; speedup vs baseline: 1.0079x; 1.0079x over previous
//
#include <hip/hip_runtime.h>
#include <hip/hip_fp16.h>
#include <math.h>

#define T_LEN 8192
#define CHN 128
#define BATCH 16
#define NKCHUNK 16   // R20: k-chunk = 512 -> grid 16x16 = 256 blocks (1/CU), halves partial traffic
#define KSTAGE 32    // k elems per LDS stage
#define NITER (T_LEN / NKCHUNK / KSTAGE)   // = 16 stage iterations per block

typedef short bf16x8 __attribute__((ext_vector_type(8)));
typedef float f32x16 __attribute__((ext_vector_type(16)));

// Native-vector complex type -> packed v_pk_* fp32 codegen (R8: -3 us fft).
typedef float cplx __attribute__((ext_vector_type(2)));
__device__ __forceinline__ cplx C2(float x, float y) { cplx r; r.x = x; r.y = y; return r; }

#define SIN8 0.3826834323650898f
#define COS8 0.9238795325112868f

// zc/zs K-CHUNKED layout [b][t>>6][chan][t&63] (R17: contiguous gram reads).
#define TCHUNK 8192              // ushorts per [tc] slab: 128 chan x 64 k
#define BPLANE (128 * TCHUNK)    // ushorts per batch per plane (= CHN*T_LEN)

// gram LDS geometry: KSTAGE=32 -> plane = 128 rows x 32 k = 8 KiB.
// Column-major swizzle: chunk (r,c) at group offset (c^(r&3))*256B +
// (r&15)*16B within the (r>>4) 1-KiB group.
#define GSP 4096                 // ushorts per plane (8 KiB)
#define GBUF (2 * GSP)           // ushorts per buffer (zc+zs planes, 16 KiB)
#define NBUF 8                   // R20: depth-8 pipeline, 8 x 16 KiB = 128 KiB LDS

typedef const __attribute__((address_space(1))) uint gld_src_t;
typedef __attribute__((address_space(3))) uint gld_dst_t;

__device__ __forceinline__ ushort f2bf(float f) {
    unsigned u = __float_as_uint(f);
    unsigned r = (u + 0x7fffu + ((u >> 16) & 1u)) >> 16;
    return (ushort)r;
}

__device__ __forceinline__ void barrier_lds_only() {
    asm volatile("s_waitcnt lgkmcnt(0)" ::: "memory");
    __builtin_amdgcn_s_barrier();
}

__device__ __forceinline__ cplx cmul(cplx a, cplx b) {
    cplx t = a.yy * b.yx;            // {ay*by, ay*bx}  (pk_mul)
    cplx r = a.xx * b;               // {ax*bx, ax*by}  (pk_mul)
    return C2(r.x - t.x, r.y + t.y);
}

__device__ __forceinline__ void r4f(cplx x0, cplx x1, cplx x2, cplx x3,
                                    cplx wa, cplx wb, cplx wc,
                                    cplx& y0, cplx& y1, cplx& y2, cplx& y3) {
    cplx t0 = x0 + x2, t1 = x0 - x2;
    cplx t2 = x1 + x3, t3 = x1 - x3;
    y0 = t0 + t2;
    y1 = cmul(t0 - t2, wb);
    y2 = cmul(C2(t1.x + t3.y, t1.y - t3.x), wa);
    y3 = cmul(C2(t1.x - t3.y, t1.y + t3.x), wc);
}

__device__ __forceinline__ void r4i(cplx x0, cplx x1, cplx x2, cplx x3,
                                    cplx wa, cplx wb, cplx wc,
                                    cplx& y0, cplx& y1, cplx& y2, cplx& y3) {
    cplx a1 = cmul(x1, wb);
    cplx a2 = cmul(x2, wa);
    cplx a3 = cmul(x3, wc);
    cplx u0 = x0 + a1, u1 = x0 - a1;
    cplx p = a2 + a3;
    cplx m = C2(-(a2.y - a3.y), a2.x - a3.x);
    y0 = u0 + p; y2 = u0 - p;
    y1 = u1 + m; y3 = u1 - m;
}

__device__ __forceinline__ void r8f(const cplx* x, float sn, float cs, cplx* y) {
    const float r22 = 0.70710678118654752f;
    cplx w1 = C2(cs, sn);
    cplx w2 = C2(cs * cs - sn * sn, 2.f * cs * sn);
    cplx w4 = cmul(w2, w2);
    cplx w6 = cmul(w4, w2);
    cplx u0 = x[0] + x[4], u1 = x[1] + x[5], u2 = x[2] + x[6], u3 = x[3] + x[7];
    cplx e0 = cmul(x[0] - x[4], w1);
    cplx e1 = cmul(x[1] - x[5], w1);
    cplx e2 = cmul(x[2] - x[6], w1);
    cplx e3 = cmul(x[3] - x[7], w1);
    cplx v0 = e0;
    cplx v1 = C2(r22 * (e1.x + e1.y), r22 * (e1.y - e1.x));
    cplx v2 = C2(e2.y, -e2.x);
    cplx v3 = C2(r22 * (e3.y - e3.x), -r22 * (e3.x + e3.y));
    r4f(u0, u1, u2, u3, w2, w4, w6, y[0], y[1], y[2], y[3]);
    r4f(v0, v1, v2, v3, w2, w4, w6, y[4], y[5], y[6], y[7]);
}

// Pass-A specialization: inputs pure real (imag = 0).
__device__ __forceinline__ void r8f_real(const float* x, float sn, float cs, cplx* y) {
    const float r22 = 0.70710678118654752f;
    cplx w2 = C2(cs * cs - sn * sn, 2.f * cs * sn);
    cplx w4 = cmul(w2, w2);
    cplx w6 = cmul(w4, w2);
    float u0 = x[0] + x[4], u1 = x[1] + x[5], u2 = x[2] + x[6], u3 = x[3] + x[7];
    float d0 = x[0] - x[4], d1 = x[1] - x[5], d2 = x[2] - x[6], d3 = x[3] - x[7];
    cplx e1 = C2(d1 * cs, d1 * sn);
    cplx e2 = C2(d2 * cs, d2 * sn);
    cplx e3 = C2(d3 * cs, d3 * sn);
    cplx v0 = C2(d0 * cs, d0 * sn);
    cplx v1 = C2(r22 * (e1.x + e1.y), r22 * (e1.y - e1.x));
    cplx v2 = C2(e2.y, -e2.x);
    cplx v3 = C2(r22 * (e3.y - e3.x), -r22 * (e3.x + e3.y));
    float t0 = u0 + u2, t1 = u0 - u2, t2 = u1 + u3, t3 = u1 - u3;
    y[0] = C2(t0 + t2, 0.f);
    float s1 = t0 - t2;
    y[1] = C2(s1 * w4.x, s1 * w4.y);
    y[2] = cmul(C2(t1, -t3), w2);
    y[3] = cmul(C2(t1, t3), w6);
    r4f(v0, v1, v2, v3, w2, w4, w6, y[4], y[5], y[6], y[7]);
}

__device__ __forceinline__ void r8i(const cplx* x, float sn, float cs, cplx* y) {
    const float r22 = 0.70710678118654752f;
    cplx w1 = C2(cs, sn);
    cplx w2 = C2(cs * cs - sn * sn, 2.f * cs * sn);
    cplx w4 = cmul(w2, w2);
    cplx w6 = cmul(w4, w2);
    cplx g0, g1, g2, g3, g4, g5, g6, g7;
    r4i(x[0], x[1], x[2], x[3], w2, w4, w6, g0, g1, g2, g3);
    r4i(x[4], x[5], x[6], x[7], w2, w4, w6, g4, g5, g6, g7);
    cplx t0 = cmul(g4, w1);
    cplx e1 = cmul(g5, w1);
    cplx e2 = cmul(g6, w1);
    cplx e3 = cmul(g7, w1);
    cplx t1 = C2(r22 * (e1.x - e1.y), r22 * (e1.x + e1.y));
    cplx t2 = C2(-e2.y, e2.x);
    cplx t3 = C2(-r22 * (e3.x + e3.y), r22 * (e3.x - e3.y));
    y[0] = g0 + t0; y[4] = g0 - t0;
    y[1] = g1 + t1; y[5] = g1 - t1;
    y[2] = g2 + t2; y[6] = g2 - t2;
    y[3] = g3 + t3; y[7] = g3 - t3;
}

// One block per (b,c) row, 512 threads — R9 version (74-75 us, VGPR 52,
// reproduced on 3 containers). R10: cross-barrier twiddle liveness costs
// +25% wall at identical VALU work — fft is stall-bound; per-pass sincos is
// free. R1-R3: 1024-thread variants spill. UNCHANGED this round.
__global__ __launch_bounds__(512, 4) void fft_analytic_kernel(const float* __restrict__ x,
                                                              ushort* __restrict__ zc,
                                                              ushort* __restrict__ zs) {
    __shared__ __align__(16) cplx buf[T_LEN];   // 64 KiB
    const int tid = threadIdx.x;
    const int row = blockIdx.x;
    const float* xr = x + ((size_t)row << 13);

    // fwd pass Q=1024 fused with global load (x real; imag folds away)
    for (int s = 0; s < 2; ++s) {
        const int g = tid + (s << 9);
        float X[8];
        cplx Y[8];
#pragma unroll
        for (int c = 0; c < 8; ++c) X[c] = xr[g + (c << 10)];
        float sn, cs;
        __sincosf(-(float)M_PI / 4096.f * (float)g, &sn, &cs);
        r8f_real(X, sn, cs, Y);
#pragma unroll
        for (int c = 0; c < 8; ++c) buf[g + (c << 10)] = Y[c];
    }
    __syncthreads();

    // fwd LDS pass Q=128
    {
        const float astep = -(float)M_PI / 512.f;
        for (int s = 0; s < 2; ++s) {
            const int g = tid + (s << 9);
            const int j = g & 127;
            const int i = ((g & ~127) << 3) | j;
            cplx xx[8], yy[8];
#pragma unroll
            for (int c = 0; c < 8; ++c) xx[c] = buf[i + c * 128];
            float sn, cs;
            __sincosf(astep * (float)j, &sn, &cs);
            r8f(xx, sn, cs, yy);
#pragma unroll
            for (int c = 0; c < 8; ++c) buf[i + c * 128] = yy[c];
        }
        __syncthreads();
    }

    // fwd LDS pass Q=16: plain reads, swizzled writes (slot = idx ^ 2c)
    {
        const float astep = -(float)M_PI / 64.f;
        for (int s = 0; s < 2; ++s) {
            const int g = tid + (s << 9);
            const int j = g & 15;
            const int i = ((g & ~15) << 3) | j;
            cplx xx[8], yy[8];
#pragma unroll
            for (int c = 0; c < 8; ++c) xx[c] = buf[i + c * 16];
            float sn, cs;
            __sincosf(astep * (float)j, &sn, &cs);
            r8f(xx, sn, cs, yy);
#pragma unroll
            for (int c = 0; c < 8; ++c) buf[(i + c * 16) ^ (2 * c)] = yy[c];
        }
        __syncthreads();
    }

    // register-local middle: thread owns elements [16*tid, 16*tid+16).
    {
        cplx v[16];
        float4* bb = (float4*)buf;
        const int K = tid & 7;
#pragma unroll
        for (int p = 0; p < 8; ++p) {
            float4 f = bb[8 * tid + (p ^ K)];
            v[2 * p]     = C2(f.x, f.y);
            v[2 * p + 1] = C2(f.z, f.w);
        }
        cplx xe[8], xo[8], E[8], O[8], t[8];
#pragma unroll
        for (int c = 0; c < 8; ++c) { xe[c] = v[2 * c]; xo[c] = v[2 * c + 1]; }
        r8f(xe, 0.f, 1.f, E);
        r8f(xo, -SIN8, COS8, O);
#pragma unroll
        for (int c = 0; c < 8; ++c) t[c] = E[c] + O[c];   // dist-1 + mask fuse
        r8i(t, 0.f, 1.f, xe);
        r8i(t, SIN8, COS8, xo);
#pragma unroll
        for (int p = 0; p < 8; ++p)
            bb[8 * tid + (p ^ K)] = make_float4(xe[p].x, xe[p].y, xo[p].x, xo[p].y);
    }
    __syncthreads();

    // inv LDS pass Q=16: swizzled reads, plain writes
    {
        const float astep = (float)M_PI / 64.f;
        for (int s = 0; s < 2; ++s) {
            const int g = tid + (s << 9);
            const int j = g & 15;
            const int i = ((g & ~15) << 3) | j;
            cplx xx[8], yy[8];
#pragma unroll
            for (int c = 0; c < 8; ++c) xx[c] = buf[(i + c * 16) ^ (2 * c)];
            float sn, cs;
            __sincosf(astep * (float)j, &sn, &cs);
            r8i(xx, sn, cs, yy);
#pragma unroll
            for (int c = 0; c < 8; ++c) buf[i + c * 16] = yy[c];
        }
        __syncthreads();
    }

    // inv LDS pass Q=128
    {
        const float astep = (float)M_PI / 512.f;
        for (int s = 0; s < 2; ++s) {
            const int g = tid + (s << 9);
            const int j = g & 127;
            const int i = ((g & ~127) << 3) | j;
            cplx xx[8], yy[8];
#pragma unroll
            for (int c = 0; c < 8; ++c) xx[c] = buf[i + c * 128];
            float sn, cs;
            __sincosf(astep * (float)j, &sn, &cs);
            r8i(xx, sn, cs, yy);
#pragma unroll
            for (int c = 0; c < 8; ++c) buf[i + c * 128] = yy[c];
        }
        __syncthreads();
    }

    // final inv pass Q=1024 fused with normalize + K-CHUNKED store:
    // element t -> plane[b][t>>6][chan][t&63]. 128 B/wave coalesced.
    {
        const size_t base = ((size_t)(row >> 7) * BPLANE) + (size_t)(row & 127) * 64;
        ushort* zcr = zc + base;
        ushort* zsr = zs + base;
        const int tk = tid & 63;
        const int tcb = tid >> 6;
        for (int s = 0; s < 2; ++s) {
            const int g = tid + (s << 9);
            cplx xx[8], yy[8];
#pragma unroll
            for (int c = 0; c < 8; ++c) xx[c] = buf[g + (c << 10)];
            float sn, cs;
            __sincosf((float)M_PI / 4096.f * (float)g, &sn, &cs);
            r8i(xx, sn, cs, yy);
#pragma unroll
            for (int c = 0; c < 8; ++c) {
                cplx vv = yy[c];
                float n2 = vv.x * vv.x + vv.y * vv.y;
                float cc = 1.f, ss = 0.f;
                if (n2 > 0.f) { float inv = rsqrtf(n2); cc = vv.x * inv; ss = vv.y * inv; }
                const int tc = tcb + s * 8 + c * 16;          // t>>6
                zcr[(size_t)tc * TCHUNK + tk] = f2bf(cc);
                zsr[(size_t)tc * TCHUNK + tk] = f2bf(ss);
            }
        }
    }
}

// MFMA Gram partials — R20 DECISIVE PROBE. R12 depth-4 was null; gram has
// been invisible (below top-5 cutoff) since R7 and every floor model says
// <=15 us while the residual is ~100 us. This round: NKCHUNK=16 (256
// blocks = 1/CU), NITER=16, DEPTH-8 pipeline (8 x 16 KiB = 128 KiB LDS —
// the gfx950 8-phase template compiles this size). Effects: (a) halves
// partial traffic (33.5 -> 16.8 MB); (b) 16-iter pipeline amortizes the
// prologue; (c) concentrates gram into half the blocks — if an unmodeled
// structural bind exists, gram's duration rises ABOVE fft and its counters
// finally appear in the top-5 for diagnosis. Win either way.
__global__ __launch_bounds__(512, 2) void gram_kernel(const ushort* __restrict__ zc,
                                                      const ushort* __restrict__ zs,
                                                      __half2* __restrict__ partial) {
    const int b = blockIdx.x, kc = blockIdx.y;
    const int tid = threadIdx.x;
    const int wave = tid >> 6;
    const int lane = tid & 63;
    const int wr = wave & 3, wcol = wave >> 2;
    const int lane31 = tid & 31;
    const int half = (tid >> 5) & 1;

    __shared__ __align__(16) ushort sZ[NBUF * GBUF];   // 128 KiB

    f32x16 accRe[2], accIm[2];
#pragma unroll
    for (int v = 0; v < 2; ++v)
#pragma unroll
        for (int r = 0; r < 16; ++r) { accRe[v][r] = 0.f; accIm[v][r] = 0.f; }

    // kc covers 8 global t-slabs; stage it covers half-slab (it&1) of slab (it>>1).
    const size_t base = (size_t)b * BPLANE + (size_t)kc * 8 * TCHUNK;

    const ushort* gsrc[2];
    int lbase[2];
#pragma unroll
    for (int q = 0; q < 2; ++q) {
        int L = (q * 8 + wave) * 64 + lane;   // 0..1023
        int plane = L >> 9;
        int P = L & 511;
        int g = P >> 6;
        int s = P & 63;
        int r = g * 16 + (s & 15);
        int c = (s >> 4) ^ (r & 3);
        gsrc[q] = (plane ? zs : zc) + base + (size_t)r * 64 + (size_t)c * 8;
        lbase[q] = (q * 8 + wave) * 512;
    }

#define STAGE(IT, BUF) do {                                                        \
        _Pragma("unroll")                                                          \
        for (int q = 0; q < 2; ++q)                                                \
            __builtin_amdgcn_global_load_lds(                                      \
                (gld_src_t*)(gsrc[q] + (size_t)((IT) >> 1) * TCHUNK                \
                                     + (size_t)((IT) & 1) * 32),                   \
                (gld_dst_t*)&sZ[(BUF) * GBUF + lbase[q]], 16, 0, 0);               \
    } while (0)

    STAGE(0, 0); STAGE(1, 1); STAGE(2, 2); STAGE(3, 3);
    STAGE(4, 4); STAGE(5, 5); STAGE(6, 6); STAGE(7, 7);

#pragma unroll
    for (int it = 0; it < NITER; ++it) {
        // counted vmcnt: retire only the oldest stage; up to 7 newer stages
        // (14 loads) stay in flight across the barrier.
        if (it <= NITER - 8)      { asm volatile("s_waitcnt vmcnt(14)" ::: "memory"); }
        else if (it == NITER - 7) { asm volatile("s_waitcnt vmcnt(12)" ::: "memory"); }
        else if (it == NITER - 6) { asm volatile("s_waitcnt vmcnt(10)" ::: "memory"); }
        else if (it == NITER - 5) { asm volatile("s_waitcnt vmcnt(8)"  ::: "memory"); }
        else if (it == NITER - 4) { asm volatile("s_waitcnt vmcnt(6)"  ::: "memory"); }
        else if (it == NITER - 3) { asm volatile("s_waitcnt vmcnt(4)"  ::: "memory"); }
        else if (it == NITER - 2) { asm volatile("s_waitcnt vmcnt(2)"  ::: "memory"); }
        else                      { asm volatile("s_waitcnt vmcnt(0)"  ::: "memory"); }
        __builtin_amdgcn_sched_barrier(0);
        __builtin_amdgcn_s_barrier();

        const ushort* S = sZ + (it & (NBUF - 1)) * GBUF;
#pragma unroll
        for (int kb = 0; kb < KSTAGE; kb += 16) {
            const int cA = (kb >> 3) + half;                   // chunk 0..3
            const int rowA = wr * 32 + lane31;
            const int aoff = ((rowA >> 4) << 9) + ((cA ^ (rowA & 3)) << 7) + ((rowA & 15) << 3);
            bf16x8 aC = *(const bf16x8*)&S[aoff];
            bf16x8 aS = *(const bf16x8*)&S[GSP + aoff];
            bf16x8 aCn;
#pragma unroll
            for (int r = 0; r < 8; ++r) aCn[r] = (short)(aC[r] ^ (short)0x8000);
            bf16x8 bC[2], bS[2];
#pragma unroll
            for (int v = 0; v < 2; ++v) {
                const int rowB = wcol * 64 + v * 32 + lane31;
                const int boff = ((rowB >> 4) << 9) + ((cA ^ (rowB & 3)) << 7) + ((rowB & 15) << 3);
                bC[v] = *(const bf16x8*)&S[boff];
                bS[v] = *(const bf16x8*)&S[GSP + boff];
            }
            accRe[0] = __builtin_amdgcn_mfma_f32_32x32x16_bf16(aC,  bC[0], accRe[0], 0, 0, 0);
            accRe[1] = __builtin_amdgcn_mfma_f32_32x32x16_bf16(aC,  bC[1], accRe[1], 0, 0, 0);
            accIm[0] = __builtin_amdgcn_mfma_f32_32x32x16_bf16(aS,  bC[0], accIm[0], 0, 0, 0);
            accIm[1] = __builtin_amdgcn_mfma_f32_32x32x16_bf16(aS,  bC[1], accIm[1], 0, 0, 0);
            accRe[0] = __builtin_amdgcn_mfma_f32_32x32x16_bf16(aS,  bS[0], accRe[0], 0, 0, 0);
            accRe[1] = __builtin_amdgcn_mfma_f32_32x32x16_bf16(aS,  bS[1], accRe[1], 0, 0, 0);
            accIm[0] = __builtin_amdgcn_mfma_f32_32x32x16_bf16(aCn, bS[0], accIm[0], 0, 0, 0);
            accIm[1] = __builtin_amdgcn_mfma_f32_32x32x16_bf16(aCn, bS[1], accIm[1], 0, 0, 0);
        }

        barrier_lds_only();
        if (it + NBUF < NITER) STAGE(it + NBUF, it & (NBUF - 1));
    }
#undef STAGE

    // C/D layout (verified m74/m101): col=lane&31, row=(reg&3)+8*(reg>>2)+4*(lane>>5)
    __half2* pb = partial + ((size_t)(kc * BATCH + b) << 14);
#pragma unroll
    for (int v = 0; v < 2; ++v)
#pragma unroll
        for (int r = 0; r < 16; ++r) {
            int rrow = (r & 3) + 8 * (r >> 2) + 4 * half;
            int i = wr * 32 + rrow;
            int j = wcol * 64 + v * 32 + lane31;
            pb[i * CHN + j] = __floats2half2_rn(accRe[v][r], accIm[v][r]);
        }
}

// Vectorized reduce (R19) — 4 outputs/thread, uint4 loads, float4 store.
// NKCHUNK=16 halves its read traffic vs R12.
__global__ __launch_bounds__(256) void reduce_kernel(const __half2* __restrict__ partial,
                                                     float* __restrict__ out) {
    const size_t n = (size_t)BATCH * CHN * CHN;
    const size_t i4 = ((size_t)blockIdx.x * 256 + threadIdx.x) * 4;
    if (i4 >= n) return;
    float re[4] = {0.f, 0.f, 0.f, 0.f}, im[4] = {0.f, 0.f, 0.f, 0.f};
#pragma unroll
    for (int c = 0; c < NKCHUNK; ++c) {
        uint4 u = *(const uint4*)&partial[(size_t)c * n + i4];
        const __half2* h = (const __half2*)&u;
#pragma unroll
        for (int k = 0; k < 4; ++k) {
            float2 p = __half22float2(h[k]);
            re[k] += p.x;
            im[k] += p.y;
        }
    }
    float4 o;
    o.x = sqrtf(re[0] * re[0] + im[0] * im[0]) * (1.0f / (float)T_LEN);
    o.y = sqrtf(re[1] * re[1] + im[1] * im[1]) * (1.0f / (float)T_LEN);
    o.z = sqrtf(re[2] * re[2] + im[2] * im[2]) * (1.0f / (float)T_LEN);
    o.w = sqrtf(re[3] * re[3] + im[3] * im[3]) * (1.0f / (float)T_LEN);
    *(float4*)&out[i4] = o;
}

extern "C" void kernel_launch(void* const* d_in, const int* in_sizes, int n_in,
                              void* d_out, int out_size, void* d_ws, size_t ws_size,
                              hipStream_t stream) {
    const float* x = (const float*)d_in[0];
    float* out = (float*)d_out;

    const size_t plane_elems = (size_t)BATCH * CHN * T_LEN;                 // 16.8M
    ushort* zc = (ushort*)d_ws;                                             // 33.55 MB
    ushort* zs = zc + plane_elems;                                          // +33.55 MB
    __half2* partial = (__half2*)((char*)d_ws + 2 * plane_elems * sizeof(ushort)); // +16.78 MB (NKCHUNK=16)

    fft_analytic_kernel<<<BATCH * CHN, 512, 0, stream>>>(x, zc, zs);

    dim3 g2(BATCH, NKCHUNK);
    gram_kernel<<<g2, 512, 0, stream>>>(zc, zs, partial);

    const int n_out = BATCH * CHN * CHN;                                    // 262144
    reduce_kernel<<<n_out / (256 * 4), 256, 0, stream>>>(partial, out);
}

// Round 14
// 172.832 us; speedup vs baseline: 1.0109x; 1.0030x over previous
//
#include <hip/hip_runtime.h>
#include <hip/hip_fp16.h>
#include <math.h>

#define T_LEN 8192
#define CHN 128
#define BATCH 16
#define NKCHUNK 16   // k-chunk = 512 -> grid 16x16 = 256 blocks (1/CU)
#define KSTAGE 32    // k elems per LDS stage
#define NITER (T_LEN / NKCHUNK / KSTAGE)   // = 16 stage iterations per block

typedef short bf16x8 __attribute__((ext_vector_type(8)));
typedef float f32x16 __attribute__((ext_vector_type(16)));

// Native-vector complex type -> packed v_pk_* fp32 codegen (R8: -3 us fft).
typedef float cplx __attribute__((ext_vector_type(2)));
__device__ __forceinline__ cplx C2(float x, float y) { cplx r; r.x = x; r.y = y; return r; }

#define SIN8 0.3826834323650898f
#define COS8 0.9238795325112868f

// zc/zs K-CHUNKED layout [b][t>>6][chan][t&63] (R17: contiguous gram reads).
#define TCHUNK 8192              // ushorts per [tc] slab: 128 chan x 64 k
#define BPLANE (128 * TCHUNK)    // ushorts per batch per plane (= CHN*T_LEN)

// gram LDS geometry: KSTAGE=32 -> plane = 128 rows x 32 k = 8 KiB.
#define GSP 4096                 // ushorts per plane (8 KiB)
#define GBUF (2 * GSP)           // ushorts per buffer (zc+zs planes, 16 KiB)
#define NBUF 8                   // depth-8 pipeline, 8 x 16 KiB = 128 KiB LDS

typedef const __attribute__((address_space(1))) uint gld_src_t;
typedef __attribute__((address_space(3))) uint gld_dst_t;

__device__ __forceinline__ ushort f2bf(float f) {
    unsigned u = __float_as_uint(f);
    unsigned r = (u + 0x7fffu + ((u >> 16) & 1u)) >> 16;
    return (ushort)r;
}

__device__ __forceinline__ void barrier_lds_only() {
    asm volatile("s_waitcnt lgkmcnt(0)" ::: "memory");
    __builtin_amdgcn_s_barrier();
}

__device__ __forceinline__ cplx cmul(cplx a, cplx b) {
    cplx t = a.yy * b.yx;            // {ay*by, ay*bx}  (pk_mul)
    cplx r = a.xx * b;               // {ax*bx, ax*by}  (pk_mul)
    return C2(r.x - t.x, r.y + t.y);
}

__device__ __forceinline__ void r4f(cplx x0, cplx x1, cplx x2, cplx x3,
                                    cplx wa, cplx wb, cplx wc,
                                    cplx& y0, cplx& y1, cplx& y2, cplx& y3) {
    cplx t0 = x0 + x2, t1 = x0 - x2;
    cplx t2 = x1 + x3, t3 = x1 - x3;
    y0 = t0 + t2;
    y1 = cmul(t0 - t2, wb);
    y2 = cmul(C2(t1.x + t3.y, t1.y - t3.x), wa);
    y3 = cmul(C2(t1.x - t3.y, t1.y + t3.x), wc);
}

__device__ __forceinline__ void r4i(cplx x0, cplx x1, cplx x2, cplx x3,
                                    cplx wa, cplx wb, cplx wc,
                                    cplx& y0, cplx& y1, cplx& y2, cplx& y3) {
    cplx a1 = cmul(x1, wb);
    cplx a2 = cmul(x2, wa);
    cplx a3 = cmul(x3, wc);
    cplx u0 = x0 + a1, u1 = x0 - a1;
    cplx p = a2 + a3;
    cplx m = C2(-(a2.y - a3.y), a2.x - a3.x);
    y0 = u0 + p; y2 = u0 - p;
    y1 = u1 + m; y3 = u1 - m;
}

__device__ __forceinline__ void r8f(const cplx* x, float sn, float cs, cplx* y) {
    const float r22 = 0.70710678118654752f;
    cplx w1 = C2(cs, sn);
    cplx w2 = C2(cs * cs - sn * sn, 2.f * cs * sn);
    cplx w4 = cmul(w2, w2);
    cplx w6 = cmul(w4, w2);
    cplx u0 = x[0] + x[4], u1 = x[1] + x[5], u2 = x[2] + x[6], u3 = x[3] + x[7];
    cplx e0 = cmul(x[0] - x[4], w1);
    cplx e1 = cmul(x[1] - x[5], w1);
    cplx e2 = cmul(x[2] - x[6], w1);
    cplx e3 = cmul(x[3] - x[7], w1);
    cplx v0 = e0;
    cplx v1 = C2(r22 * (e1.x + e1.y), r22 * (e1.y - e1.x));
    cplx v2 = C2(e2.y, -e2.x);
    cplx v3 = C2(r22 * (e3.y - e3.x), -r22 * (e3.x + e3.y));
    r4f(u0, u1, u2, u3, w2, w4, w6, y[0], y[1], y[2], y[3]);
    r4f(v0, v1, v2, v3, w2, w4, w6, y[4], y[5], y[6], y[7]);
}

// Pass-A specialization: inputs pure real (imag = 0).
__device__ __forceinline__ void r8f_real(const float* x, float sn, float cs, cplx* y) {
    const float r22 = 0.70710678118654752f;
    cplx w2 = C2(cs * cs - sn * sn, 2.f * cs * sn);
    cplx w4 = cmul(w2, w2);
    cplx w6 = cmul(w4, w2);
    float u0 = x[0] + x[4], u1 = x[1] + x[5], u2 = x[2] + x[6], u3 = x[3] + x[7];
    float d0 = x[0] - x[4], d1 = x[1] - x[5], d2 = x[2] - x[6], d3 = x[3] - x[7];
    cplx e1 = C2(d1 * cs, d1 * sn);
    cplx e2 = C2(d2 * cs, d2 * sn);
    cplx e3 = C2(d3 * cs, d3 * sn);
    cplx v0 = C2(d0 * cs, d0 * sn);
    cplx v1 = C2(r22 * (e1.x + e1.y), r22 * (e1.y - e1.x));
    cplx v2 = C2(e2.y, -e2.x);
    cplx v3 = C2(r22 * (e3.y - e3.x), -r22 * (e3.x + e3.y));
    float t0 = u0 + u2, t1 = u0 - u2, t2 = u1 + u3, t3 = u1 - u3;
    y[0] = C2(t0 + t2, 0.f);
    float s1 = t0 - t2;
    y[1] = C2(s1 * w4.x, s1 * w4.y);
    y[2] = cmul(C2(t1, -t3), w2);
    y[3] = cmul(C2(t1, t3), w6);
    r4f(v0, v1, v2, v3, w2, w4, w6, y[4], y[5], y[6], y[7]);
}

__device__ __forceinline__ void r8i(const cplx* x, float sn, float cs, cplx* y) {
    const float r22 = 0.70710678118654752f;
    cplx w1 = C2(cs, sn);
    cplx w2 = C2(cs * cs - sn * sn, 2.f * cs * sn);
    cplx w4 = cmul(w2, w2);
    cplx w6 = cmul(w4, w2);
    cplx g0, g1, g2, g3, g4, g5, g6, g7;
    r4i(x[0], x[1], x[2], x[3], w2, w4, w6, g0, g1, g2, g3);
    r4i(x[4], x[5], x[6], x[7], w2, w4, w6, g4, g5, g6, g7);
    cplx t0 = cmul(g4, w1);
    cplx e1 = cmul(g5, w1);
    cplx e2 = cmul(g6, w1);
    cplx e3 = cmul(g7, w1);
    cplx t1 = C2(r22 * (e1.x - e1.y), r22 * (e1.x + e1.y));
    cplx t2 = C2(-e2.y, e2.x);
    cplx t3 = C2(-r22 * (e3.x + e3.y), r22 * (e3.x - e3.y));
    y[0] = g0 + t0; y[4] = g0 - t0;
    y[1] = g1 + t1; y[5] = g1 - t1;
    y[2] = g2 + t2; y[6] = g2 - t2;
    y[3] = g3 + t3; y[7] = g3 - t3;
}

// R21: FUSED s-halves. fft is LDS-occupancy-capped (64 KiB buf -> 2 blk/CU
// = 50% max, 37% measured) and stall-bound (VALUBusy 68%). The two s-halves
// of every pass touch DISJOINT elements, so they fuse into one straight-
// line block: 16 loads issued together, two independent butterfly chains
// interleaved by the scheduler, 16 stores. Doubles per-wave ILP with
// PASS-LOCAL state only (R10 lesson: cross-barrier liveness kills; this
// has none). Bonus: j is s-invariant for passes B/C/D/E (512 = 0 mod
// 128/16) -> one sincos per pass instead of two.
// R1-R3: 1024-thread variants spill; do not revisit.
__global__ __launch_bounds__(512, 4) void fft_analytic_kernel(const float* __restrict__ x,
                                                              ushort* __restrict__ zc,
                                                              ushort* __restrict__ zs) {
    __shared__ __align__(16) cplx buf[T_LEN];   // 64 KiB
    const int tid = threadIdx.x;
    const int row = blockIdx.x;
    const float* xr = x + ((size_t)row << 13);

    // pass A: fwd radix-8 stride 1024, both halves, fused with global load
    {
        float X0[8], X1[8];
        cplx Y0[8], Y1[8];
#pragma unroll
        for (int c = 0; c < 8; ++c) X0[c] = xr[tid + (c << 10)];
#pragma unroll
        for (int c = 0; c < 8; ++c) X1[c] = xr[tid + 512 + (c << 10)];
        float sn0, cs0, sn1, cs1;
        __sincosf(-(float)M_PI / 4096.f * (float)tid, &sn0, &cs0);
        __sincosf(-(float)M_PI / 4096.f * (float)(tid + 512), &sn1, &cs1);
        r8f_real(X0, sn0, cs0, Y0);
        r8f_real(X1, sn1, cs1, Y1);
#pragma unroll
        for (int c = 0; c < 8; ++c) buf[tid + (c << 10)] = Y0[c];
#pragma unroll
        for (int c = 0; c < 8; ++c) buf[tid + 512 + (c << 10)] = Y1[c];
    }
    __syncthreads();

    // pass B: fwd radix-8 stride 128; j s-invariant -> one sincos
    {
        const int j = tid & 127;
        const int i0 = ((tid & ~127) << 3) | j;
        const int i1 = i0 + 4096;
        cplx x0[8], x1[8], y0[8], y1[8];
#pragma unroll
        for (int c = 0; c < 8; ++c) x0[c] = buf[i0 + (c << 7)];
#pragma unroll
        for (int c = 0; c < 8; ++c) x1[c] = buf[i1 + (c << 7)];
        float sn, cs;
        __sincosf(-(float)M_PI / 512.f * (float)j, &sn, &cs);
        r8f(x0, sn, cs, y0);
        r8f(x1, sn, cs, y1);
#pragma unroll
        for (int c = 0; c < 8; ++c) buf[i0 + (c << 7)] = y0[c];
#pragma unroll
        for (int c = 0; c < 8; ++c) buf[i1 + (c << 7)] = y1[c];
    }
    __syncthreads();

    // pass C: fwd radix-8 stride 16; plain reads, swizzled writes (^2c)
    {
        const int j = tid & 15;
        const int i0 = ((tid & ~15) << 3) | j;
        const int i1 = i0 + 4096;
        cplx x0[8], x1[8], y0[8], y1[8];
#pragma unroll
        for (int c = 0; c < 8; ++c) x0[c] = buf[i0 + (c << 4)];
#pragma unroll
        for (int c = 0; c < 8; ++c) x1[c] = buf[i1 + (c << 4)];
        float sn, cs;
        __sincosf(-(float)M_PI / 64.f * (float)j, &sn, &cs);
        r8f(x0, sn, cs, y0);
        r8f(x1, sn, cs, y1);
#pragma unroll
        for (int c = 0; c < 8; ++c) buf[(i0 + (c << 4)) ^ (2 * c)] = y0[c];
#pragma unroll
        for (int c = 0; c < 8; ++c) buf[(i1 + (c << 4)) ^ (2 * c)] = y1[c];
    }
    __syncthreads();

    // register-local middle: thread owns elements [16*tid, 16*tid+16).
    {
        cplx v[16];
        float4* bb = (float4*)buf;
        const int K = tid & 7;
#pragma unroll
        for (int p = 0; p < 8; ++p) {
            float4 f = bb[8 * tid + (p ^ K)];
            v[2 * p]     = C2(f.x, f.y);
            v[2 * p + 1] = C2(f.z, f.w);
        }
        cplx xe[8], xo[8], E[8], O[8], t[8];
#pragma unroll
        for (int c = 0; c < 8; ++c) { xe[c] = v[2 * c]; xo[c] = v[2 * c + 1]; }
        r8f(xe, 0.f, 1.f, E);
        r8f(xo, -SIN8, COS8, O);
#pragma unroll
        for (int c = 0; c < 8; ++c) t[c] = E[c] + O[c];   // dist-1 + mask fuse
        r8i(t, 0.f, 1.f, xe);
        r8i(t, SIN8, COS8, xo);
#pragma unroll
        for (int p = 0; p < 8; ++p)
            bb[8 * tid + (p ^ K)] = make_float4(xe[p].x, xe[p].y, xo[p].x, xo[p].y);
    }
    __syncthreads();

    // pass D: inv radix-8 stride 16: swizzled reads, plain writes
    {
        const int j = tid & 15;
        const int i0 = ((tid & ~15) << 3) | j;
        const int i1 = i0 + 4096;
        cplx x0[8], x1[8], y0[8], y1[8];
#pragma unroll
        for (int c = 0; c < 8; ++c) x0[c] = buf[(i0 + (c << 4)) ^ (2 * c)];
#pragma unroll
        for (int c = 0; c < 8; ++c) x1[c] = buf[(i1 + (c << 4)) ^ (2 * c)];
        float sn, cs;
        __sincosf((float)M_PI / 64.f * (float)j, &sn, &cs);
        r8i(x0, sn, cs, y0);
        r8i(x1, sn, cs, y1);
#pragma unroll
        for (int c = 0; c < 8; ++c) buf[i0 + (c << 4)] = y0[c];
#pragma unroll
        for (int c = 0; c < 8; ++c) buf[i1 + (c << 4)] = y1[c];
    }
    __syncthreads();

    // pass E: inv radix-8 stride 128
    {
        const int j = tid & 127;
        const int i0 = ((tid & ~127) << 3) | j;
        const int i1 = i0 + 4096;
        cplx x0[8], x1[8], y0[8], y1[8];
#pragma unroll
        for (int c = 0; c < 8; ++c) x0[c] = buf[i0 + (c << 7)];
#pragma unroll
        for (int c = 0; c < 8; ++c) x1[c] = buf[i1 + (c << 7)];
        float sn, cs;
        __sincosf((float)M_PI / 512.f * (float)j, &sn, &cs);
        r8i(x0, sn, cs, y0);
        r8i(x1, sn, cs, y1);
#pragma unroll
        for (int c = 0; c < 8; ++c) buf[i0 + (c << 7)] = y0[c];
#pragma unroll
        for (int c = 0; c < 8; ++c) buf[i1 + (c << 7)] = y1[c];
    }
    __syncthreads();

    // pass F: inv radix-8 stride 1024, both halves, + normalize + K-CHUNKED
    // store: element t -> plane[b][t>>6][chan][t&63]. 128 B/wave coalesced.
    {
        const size_t base = ((size_t)(row >> 7) * BPLANE) + (size_t)(row & 127) * 64;
        ushort* zcr = zc + base;
        ushort* zsr = zs + base;
        const int tk = tid & 63;
        const int tcb = tid >> 6;
        cplx x0[8], x1[8], y0[8], y1[8];
#pragma unroll
        for (int c = 0; c < 8; ++c) x0[c] = buf[tid + (c << 10)];
#pragma unroll
        for (int c = 0; c < 8; ++c) x1[c] = buf[tid + 512 + (c << 10)];
        float sn0, cs0, sn1, cs1;
        __sincosf((float)M_PI / 4096.f * (float)tid, &sn0, &cs0);
        __sincosf((float)M_PI / 4096.f * (float)(tid + 512), &sn1, &cs1);
        r8i(x0, sn0, cs0, y0);
        r8i(x1, sn1, cs1, y1);
#pragma unroll
        for (int c = 0; c < 8; ++c) {
            cplx vv = y0[c];
            float n2 = vv.x * vv.x + vv.y * vv.y;
            float cc = 1.f, ss = 0.f;
            if (n2 > 0.f) { float inv = rsqrtf(n2); cc = vv.x * inv; ss = vv.y * inv; }
            const int tc = tcb + c * 16;                      // t>>6 (half 0)
            zcr[(size_t)tc * TCHUNK + tk] = f2bf(cc);
            zsr[(size_t)tc * TCHUNK + tk] = f2bf(ss);
        }
#pragma unroll
        for (int c = 0; c < 8; ++c) {
            cplx vv = y1[c];
            float n2 = vv.x * vv.x + vv.y * vv.y;
            float cc = 1.f, ss = 0.f;
            if (n2 > 0.f) { float inv = rsqrtf(n2); cc = vv.x * inv; ss = vv.y * inv; }
            const int tc = tcb + 8 + c * 16;                  // t>>6 (half 1)
            zcr[(size_t)tc * TCHUNK + tk] = f2bf(cc);
            zsr[(size_t)tc * TCHUNK + tk] = f2bf(ss);
        }
    }
}

// MFMA Gram partials — byte-identical to R13 (gram line of attack paused:
// depth-3/4/8 x 256/512 blocks all within noise; gram < fft at both
// concentrations; needs counters before further edits).
__global__ __launch_bounds__(512, 2) void gram_kernel(const ushort* __restrict__ zc,
                                                      const ushort* __restrict__ zs,
                                                      __half2* __restrict__ partial) {
    const int b = blockIdx.x, kc = blockIdx.y;
    const int tid = threadIdx.x;
    const int wave = tid >> 6;
    const int lane = tid & 63;
    const int wr = wave & 3, wcol = wave >> 2;
    const int lane31 = tid & 31;
    const int half = (tid >> 5) & 1;

    __shared__ __align__(16) ushort sZ[NBUF * GBUF];   // 128 KiB

    f32x16 accRe[2], accIm[2];
#pragma unroll
    for (int v = 0; v < 2; ++v)
#pragma unroll
        for (int r = 0; r < 16; ++r) { accRe[v][r] = 0.f; accIm[v][r] = 0.f; }

    const size_t base = (size_t)b * BPLANE + (size_t)kc * 8 * TCHUNK;

    const ushort* gsrc[2];
    int lbase[2];
#pragma unroll
    for (int q = 0; q < 2; ++q) {
        int L = (q * 8 + wave) * 64 + lane;   // 0..1023
        int plane = L >> 9;
        int P = L & 511;
        int g = P >> 6;
        int s = P & 63;
        int r = g * 16 + (s & 15);
        int c = (s >> 4) ^ (r & 3);
        gsrc[q] = (plane ? zs : zc) + base + (size_t)r * 64 + (size_t)c * 8;
        lbase[q] = (q * 8 + wave) * 512;
    }

#define STAGE(IT, BUF) do {                                                        \
        _Pragma("unroll")                                                          \
        for (int q = 0; q < 2; ++q)                                                \
            __builtin_amdgcn_global_load_lds(                                      \
                (gld_src_t*)(gsrc[q] + (size_t)((IT) >> 1) * TCHUNK                \
                                     + (size_t)((IT) & 1) * 32),                   \
                (gld_dst_t*)&sZ[(BUF) * GBUF + lbase[q]], 16, 0, 0);               \
    } while (0)

    STAGE(0, 0); STAGE(1, 1); STAGE(2, 2); STAGE(3, 3);
    STAGE(4, 4); STAGE(5, 5); STAGE(6, 6); STAGE(7, 7);

#pragma unroll
    for (int it = 0; it < NITER; ++it) {
        if (it <= NITER - 8)      { asm volatile("s_waitcnt vmcnt(14)" ::: "memory"); }
        else if (it == NITER - 7) { asm volatile("s_waitcnt vmcnt(12)" ::: "memory"); }
        else if (it == NITER - 6) { asm volatile("s_waitcnt vmcnt(10)" ::: "memory"); }
        else if (it == NITER - 5) { asm volatile("s_waitcnt vmcnt(8)"  ::: "memory"); }
        else if (it == NITER - 4) { asm volatile("s_waitcnt vmcnt(6)"  ::: "memory"); }
        else if (it == NITER - 3) { asm volatile("s_waitcnt vmcnt(4)"  ::: "memory"); }
        else if (it == NITER - 2) { asm volatile("s_waitcnt vmcnt(2)"  ::: "memory"); }
        else                      { asm volatile("s_waitcnt vmcnt(0)"  ::: "memory"); }
        __builtin_amdgcn_sched_barrier(0);
        __builtin_amdgcn_s_barrier();

        const ushort* S = sZ + (it & (NBUF - 1)) * GBUF;
#pragma unroll
        for (int kb = 0; kb < KSTAGE; kb += 16) {
            const int cA = (kb >> 3) + half;                   // chunk 0..3
            const int rowA = wr * 32 + lane31;
            const int aoff = ((rowA >> 4) << 9) + ((cA ^ (rowA & 3)) << 7) + ((rowA & 15) << 3);
            bf16x8 aC = *(const bf16x8*)&S[aoff];
            bf16x8 aS = *(const bf16x8*)&S[GSP + aoff];
            bf16x8 aCn;
#pragma unroll
            for (int r = 0; r < 8; ++r) aCn[r] = (short)(aC[r] ^ (short)0x8000);
            bf16x8 bC[2], bS[2];
#pragma unroll
            for (int v = 0; v < 2; ++v) {
                const int rowB = wcol * 64 + v * 32 + lane31;
                const int boff = ((rowB >> 4) << 9) + ((cA ^ (rowB & 3)) << 7) + ((rowB & 15) << 3);
                bC[v] = *(const bf16x8*)&S[boff];
                bS[v] = *(const bf16x8*)&S[GSP + boff];
            }
            accRe[0] = __builtin_amdgcn_mfma_f32_32x32x16_bf16(aC,  bC[0], accRe[0], 0, 0, 0);
            accRe[1] = __builtin_amdgcn_mfma_f32_32x32x16_bf16(aC,  bC[1], accRe[1], 0, 0, 0);
            accIm[0] = __builtin_amdgcn_mfma_f32_32x32x16_bf16(aS,  bC[0], accIm[0], 0, 0, 0);
            accIm[1] = __builtin_amdgcn_mfma_f32_32x32x16_bf16(aS,  bC[1], accIm[1], 0, 0, 0);
            accRe[0] = __builtin_amdgcn_mfma_f32_32x32x16_bf16(aS,  bS[0], accRe[0], 0, 0, 0);
            accRe[1] = __builtin_amdgcn_mfma_f32_32x32x16_bf16(aS,  bS[1], accRe[1], 0, 0, 0);
            accIm[0] = __builtin_amdgcn_mfma_f32_32x32x16_bf16(aCn, bS[0], accIm[0], 0, 0, 0);
            accIm[1] = __builtin_amdgcn_mfma_f32_32x32x16_bf16(aCn, bS[1], accIm[1], 0, 0, 0);
        }

        barrier_lds_only();
        if (it + NBUF < NITER) STAGE(it + NBUF, it & (NBUF - 1));
    }
#undef STAGE

    // C/D layout (verified m74/m101): col=lane&31, row=(reg&3)+8*(reg>>2)+4*(lane>>5)
    __half2* pb = partial + ((size_t)(kc * BATCH + b) << 14);
#pragma unroll
    for (int v = 0; v < 2; ++v)
#pragma unroll
        for (int r = 0; r < 16; ++r) {
            int rrow = (r & 3) + 8 * (r >> 2) + 4 * half;
            int i = wr * 32 + rrow;
            int j = wcol * 64 + v * 32 + lane31;
            pb[i * CHN + j] = __floats2half2_rn(accRe[v][r], accIm[v][r]);
        }
}

// Vectorized reduce — 4 outputs/thread, uint4 loads, float4 store.
__global__ __launch_bounds__(256) void reduce_kernel(const __half2* __restrict__ partial,
                                                     float* __restrict__ out) {
    const size_t n = (size_t)BATCH * CHN * CHN;
    const size_t i4 = ((size_t)blockIdx.x * 256 + threadIdx.x) * 4;
    if (i4 >= n) return;
    float re[4] = {0.f, 0.f, 0.f, 0.f}, im[4] = {0.f, 0.f, 0.f, 0.f};
#pragma unroll
    for (int c = 0; c < NKCHUNK; ++c) {
        uint4 u = *(const uint4*)&partial[(size_t)c * n + i4];
        const __half2* h = (const __half2*)&u;
#pragma unroll
        for (int k = 0; k < 4; ++k) {
            float2 p = __half22float2(h[k]);
            re[k] += p.x;
            im[k] += p.y;
        }
    }
    float4 o;
    o.x = sqrtf(re[0] * re[0] + im[0] * im[0]) * (1.0f / (float)T_LEN);
    o.y = sqrtf(re[1] * re[1] + im[1] * im[1]) * (1.0f / (float)T_LEN);
    o.z = sqrtf(re[2] * re[2] + im[2] * im[2]) * (1.0f / (float)T_LEN);
    o.w = sqrtf(re[3] * re[3] + im[3] * im[3]) * (1.0f / (float)T_LEN);
    *(float4*)&out[i4] = o;
}

extern "C" void kernel_launch(void* const* d_in, const int* in_sizes, int n_in,
                              void* d_out, int out_size, void* d_ws, size_t ws_size,
                              hipStream_t stream) {
    const float* x = (const float*)d_in[0];
    float* out = (float*)d_out;

    const size_t plane_elems = (size_t)BATCH * CHN * T_LEN;                 // 16.8M
    ushort* zc = (ushort*)d_ws;                                             // 33.55 MB
    ushort* zs = zc + plane_elems;                                          // +33.55 MB
    __half2* partial = (__half2*)((char*)d_ws + 2 * plane_elems * sizeof(ushort)); // +16.78 MB (NKCHUNK=16)

    fft_analytic_kernel<<<BATCH * CHN, 512, 0, stream>>>(x, zc, zs);

    dim3 g2(BATCH, NKCHUNK);
    gram_kernel<<<g2, 512, 0, stream>>>(zc, zs, partial);

    const int n_out = BATCH * CHN * CHN;                                    // 262144
    reduce_kernel<<<n_out / (256 * 4), 256, 0, stream>>>(partial, out);
}